// Round 5
// baseline (337.029 us; speedup 1.0000x reference)
//
#include <hip/hip_runtime.h>
#include <hip/hip_bf16.h>
#include <hip/hip_fp16.h>
#include <stdint.h>

// LightGCN on MI355X, round 8.
// R7 post-mortem: spmv at gather-path floor (VALU 35%, HBM 47%, FETCH
// 175MB); but 150us of 324 is CSR build + overheads, with k_build at 196
// blocks = 1 block/CU (no latency hiding). Also each spmv pays a 51MB
// fp32 acc RMW that is algebraically removable.
// R8: (1) 128-node buckets (NB=782): k_build 782 blocks (~3/CU).
// (2) spmv passes write ONLY z_{k+1}=x_k*dinv (fp16); final pass recovers
//     x_k = z_k*sqrt(deg) in its epilogue (dinv=0 => z=0 => x=0 correct).
//     Per-node {base,deg,dinv} packed in one int4 broadcast load.
// (3) z double-buffer zA<->zB as before; zero row at z[N_NODES].

#define N_NODES 100000
#define N_EDGES 3200000
#define DIM 64

#define BSH 7                // 128 nodes per bucket
#define BNODES 128
#define NB 782               // ceil(100000/128)
#define CAP 4608             // staging slots per bucket (mean 4092, +8 sigma)

#define CHUNK 4096           // edges per k_bucket block
#define NBLK1 ((N_EDGES + CHUNK - 1) / CHUNK)  // 782

// ---- level 1: bucket edges by dst range (dst>>7) ----
__global__ __launch_bounds__(256) void k_bucket(const int* __restrict__ ei,
                                                int* __restrict__ gcursor,
                                                int* __restrict__ staging) {
    __shared__ int stage[CHUNK];            // packed (row<<7)|dstLocal
    __shared__ unsigned short sbkt[CHUNK];  // bucket id per staged entry
    __shared__ int bcnt[NB];
    __shared__ int boff[NB];
    __shared__ int bstart[NB];
    __shared__ int gbase[NB];
    __shared__ int wtt[4];

    int t = threadIdx.x;
    int e0 = blockIdx.x * CHUNK;
    int nblk = min(CHUNK, N_EDGES - e0);
    int nvec = nblk >> 2;

    const int4* col4 = (const int4*)(ei + N_EDGES + e0);
    const int4* row4 = (const int4*)(ei + e0);

    for (int i = t; i < NB; i += 256) { bcnt[i] = 0; boff[i] = 0; }
    __syncthreads();

    // phase A: count per bucket
    for (int i = t; i < nvec; i += 256) {
        int4 c = col4[i];
        atomicAdd(&bcnt[c.x >> BSH], 1);
        atomicAdd(&bcnt[c.y >> BSH], 1);
        atomicAdd(&bcnt[c.z >> BSH], 1);
        atomicAdd(&bcnt[c.w >> BSH], 1);
    }
    __syncthreads();

    // phase B: exclusive scan of bcnt (4 items/thread) -> bstart; reserve
    // global runs via gcursor
    {
        int v[4];
        int s = 0;
#pragma unroll
        for (int k = 0; k < 4; k++) {
            int j = t * 4 + k;
            v[k] = (j < NB) ? bcnt[j] : 0;
            s += v[k];
        }
        int lane = t & 63, w = t >> 6;
        int ss = s;
#pragma unroll
        for (int off = 1; off < 64; off <<= 1) {
            int u = __shfl_up(ss, off);
            if (lane >= off) ss += u;
        }
        if (lane == 63) wtt[w] = ss;
        __syncthreads();
        int wo = 0;
        for (int ww = 0; ww < w; ww++) wo += wtt[ww];
        int run = ss - s + wo;
#pragma unroll
        for (int k = 0; k < 4; k++) {
            int j = t * 4 + k;
            if (j < NB) {
                bstart[j] = run;
                gbase[j] = (v[k] > 0) ? atomicAdd(&gcursor[j], v[k]) : 0;
            }
            run += v[k];
        }
    }
    __syncthreads();

    // phase C: place edges into LDS, bucket-sorted; remember bucket id
    for (int i = t; i < nvec; i += 256) {
        int4 c = col4[i];
        int4 r = row4[i];
        int b0 = c.x >> BSH, b1 = c.y >> BSH, b2 = c.z >> BSH, b3 = c.w >> BSH;
        int p0 = bstart[b0] + atomicAdd(&boff[b0], 1);
        int p1 = bstart[b1] + atomicAdd(&boff[b1], 1);
        int p2 = bstart[b2] + atomicAdd(&boff[b2], 1);
        int p3 = bstart[b3] + atomicAdd(&boff[b3], 1);
        stage[p0] = (r.x << BSH) | (c.x & (BNODES - 1)); sbkt[p0] = (unsigned short)b0;
        stage[p1] = (r.y << BSH) | (c.y & (BNODES - 1)); sbkt[p1] = (unsigned short)b1;
        stage[p2] = (r.z << BSH) | (c.z & (BNODES - 1)); sbkt[p2] = (unsigned short)b2;
        stage[p3] = (r.w << BSH) | (c.w & (BNODES - 1)); sbkt[p3] = (unsigned short)b3;
    }
    __syncthreads();

    // phase D: flush runs contiguously (coalesced across the wave)
    for (int i = t; i < nblk; i += 256) {
        int e = stage[i];
        int b = sbkt[i];
        staging[(size_t)b * CAP + gbase[b] + (i - bstart[b])] = e;
    }
}

// ---- exclusive scan over 782 bucket totals (1 block, 4 items/thread) ----
__global__ void k_bstart(const int* __restrict__ gcursor, int* __restrict__ bucketStart) {
    __shared__ int wtt[4];
    int t = threadIdx.x;
    int v[4];
    int s = 0;
#pragma unroll
    for (int k = 0; k < 4; k++) {
        int j = t * 4 + k;
        v[k] = (j < NB) ? gcursor[j] : 0;
        s += v[k];
    }
    int lane = t & 63, w = t >> 6;
    int ss = s;
#pragma unroll
    for (int off = 1; off < 64; off <<= 1) {
        int u = __shfl_up(ss, off);
        if (lane >= off) ss += u;
    }
    if (lane == 63) wtt[w] = ss;
    __syncthreads();
    int wo = 0;
    for (int ww = 0; ww < w; ww++) wo += wtt[ww];
    int run = ss - s + wo;
#pragma unroll
    for (int k = 0; k < 4; k++) {
        int j = t * 4 + k;
        if (j < NB) bucketStart[j] = run;
        run += v[k];
    }
}

// ---- level 2: per-bucket CSR build (count + scan + scatter, one owner) ----
// Emits nodeRec = {base, deg, dinv_bits, 0} per node + dinv array.
__global__ __launch_bounds__(256) void k_build(const int* __restrict__ gcursor,
                                               const int* __restrict__ bucketStart,
                                               const int* __restrict__ staging,
                                               int4* __restrict__ rec,
                                               float* __restrict__ dinv,
                                               int* __restrict__ csrc) {
    __shared__ int ldeg[BNODES];
    __shared__ int lcur[BNODES];
    __shared__ int wtt[4];

    int b = blockIdx.x;
    int t = threadIdx.x;
    int n0 = b << BSH;
    int nloc = min(BNODES, N_NODES - n0);
    int cnt = gcursor[b];
    const int* st = staging + (size_t)b * CAP;

    if (t < BNODES) ldeg[t] = 0;
    __syncthreads();

    // count per dst
    for (int i = t; i < cnt; i += 256) {
        atomicAdd(&ldeg[st[i] & (BNODES - 1)], 1);
    }
    __syncthreads();

    // scan over 128 counters (threads 0..127; others carry zeros)
    int a = (t < BNODES) ? ldeg[t] : 0;
    int lane = t & 63, w = t >> 6;
    int ss = a;
#pragma unroll
    for (int off = 1; off < 64; off <<= 1) {
        int u = __shfl_up(ss, off);
        if (lane >= off) ss += u;
    }
    if (lane == 63) wtt[w] = ss;
    __syncthreads();
    int wo = 0;
    for (int ww = 0; ww < w; ww++) wo += wtt[ww];
    int excl = ss - a + wo;
    int gb = bucketStart[b] + excl;

    if (t < BNODES) {
        lcur[t] = gb;
        if (t < nloc) {
            int n = n0 + t;
            float di = (a > 0) ? rsqrtf((float)a) : 0.0f;
            rec[n] = make_int4(gb, a, __float_as_int(di), 0);
            dinv[n] = di;
        }
    }
    __syncthreads();

    // scatter rows into this bucket's csrc range (L2-resident, single owner)
    for (int i = t; i < cnt; i += 256) {
        int e = st[i];
        int p = atomicAdd(&lcur[e & (BNODES - 1)], 1);
        csrc[p] = e >> BSH;
    }
}

// z0 = fp16(emb * dinv[node]); tail threads zero the zero rows of zA/zB
__global__ void k_z0(const float* __restrict__ emb, const float* __restrict__ dinv,
                     __half* __restrict__ zA, __half* __restrict__ zB) {
    const int total = (N_NODES * DIM) / 4;  // 1.6M groups of 4
    int i = blockIdx.x * blockDim.x + threadIdx.x;
    if (i >= total) {
        int r = i - total;
        if (r < 16) ((uint2*)(zA + (size_t)N_NODES * DIM))[r] = make_uint2(0, 0);
        else if (r < 32) ((uint2*)(zB + (size_t)N_NODES * DIM))[r - 16] = make_uint2(0, 0);
        return;
    }
    float di = dinv[(i * 4) >> 6];
    const float4 v = ((const float4*)emb)[i];
    union { ushort h[4]; uint2 u; } pk;
    __half h0 = __float2half(v.x * di);
    __half h1 = __float2half(v.y * di);
    __half h2 = __float2half(v.z * di);
    __half h3 = __float2half(v.w * di);
    pk.h[0] = *(ushort*)&h0; pk.h[1] = *(ushort*)&h1;
    pk.h[2] = *(ushort*)&h2; pk.h[3] = *(ushort*)&h3;
    ((uint2*)zA)[i] = pk.u;
}

// ---- SpMV: one wave per dst node; exact ceil(deg/8) gather groups of 8;
// fp16 rows, packed half2 accumulate; invalid slots -> zero row.
// mode 0: write z_out = x*dinv (fp16) only.
// mode 2: final: out = 0.25*(emb + sqrt(deg)*(z2+z3) + x3); no z write.
__global__ __launch_bounds__(256) void k_spmv(
    const int4* __restrict__ rec, const int* __restrict__ csrc,
    const __half* __restrict__ z, __half* __restrict__ znext,
    const __half* __restrict__ zprev, const float* __restrict__ emb,
    float* __restrict__ out, int mode) {
    int wave = (blockIdx.x * blockDim.x + threadIdx.x) >> 6;
    int lane = threadIdx.x & 63;
    if (wave >= N_NODES) return;
    int g = lane >> 3;   // edge slot within group 0..7
    int l = lane & 7;    // feature chunk: features [l*8, l*8+8)

    int4 nr = rec[wave];          // broadcast load
    int start = nr.x;
    int cnt = nr.y;
    float di = __int_as_float(nr.z);
    int ng = (cnt + 7) >> 3;      // gather groups (wave-uniform)

    __half2 hz = __float2half2_rn(0.0f);
    __half2 hacc0 = hz, hacc1 = hz, hacc2 = hz, hacc3 = hz;

#define GLOAD(KK, SVAR)                              \
    int e##SVAR = (KK) * 8 + g;                      \
    int SVAR = csrc[start + e##SVAR];                \
    SVAR = (e##SVAR < cnt) ? SVAR : N_NODES;

#define GACC(SVAR)                                                        \
    do {                                                                  \
        uint4 v = *((const uint4*)(z + ((size_t)SVAR << 6)) + l);         \
        const __half2* hv = (const __half2*)&v;                           \
        hacc0 = __hadd2(hacc0, hv[0]);                                    \
        hacc1 = __hadd2(hacc1, hv[1]);                                    \
        hacc2 = __hadd2(hacc2, hv[2]);                                    \
        hacc3 = __hadd2(hacc3, hv[3]);                                    \
    } while (0)

    int k = 0;
    for (; k + 4 <= ng; k += 4) {
        GLOAD(k + 0, s0); GLOAD(k + 1, s1); GLOAD(k + 2, s2); GLOAD(k + 3, s3);
        GACC(s0); GACC(s1); GACC(s2); GACC(s3);
    }
    int rem = ng - k;           // wave-uniform 0..3
    if (rem > 0) {
        GLOAD(k + 0, t0);
        if (rem > 1) { GLOAD(k + 1, t1);
            if (rem > 2) { GLOAD(k + 2, t2); GACC(t0); GACC(t1); GACC(t2); }
            else { GACC(t0); GACC(t1); }
        } else { GACC(t0); }
    }
#undef GLOAD
#undef GACC

    // packed reduce across the 8 edge-slot groups (lane bits 3,4,5)
#pragma unroll
    for (int off = 8; off <= 32; off <<= 1) {
        int b0 = __shfl_xor(*(int*)&hacc0, off);
        int b1 = __shfl_xor(*(int*)&hacc1, off);
        int b2 = __shfl_xor(*(int*)&hacc2, off);
        int b3 = __shfl_xor(*(int*)&hacc3, off);
        hacc0 = __hadd2(hacc0, *(__half2*)&b0);
        hacc1 = __hadd2(hacc1, *(__half2*)&b1);
        hacc2 = __hadd2(hacc2, *(__half2*)&b2);
        hacc3 = __hadd2(hacc3, *(__half2*)&b3);
    }

    if (lane < 8) {  // lane == l, holds features [l*8, l*8+8)
        size_t o = (size_t)wave * DIM + lane * 8;
        float x[8];   // x_{k+1} for this node = di * sum
        x[0] = __low2float(hacc0) * di; x[1] = __high2float(hacc0) * di;
        x[2] = __low2float(hacc1) * di; x[3] = __high2float(hacc1) * di;
        x[4] = __low2float(hacc2) * di; x[5] = __high2float(hacc2) * di;
        x[6] = __low2float(hacc3) * di; x[7] = __high2float(hacc3) * di;

        if (mode == 0) {
            union { ushort h[8]; uint4 u; } pk;
#pragma unroll
            for (int j = 0; j < 8; j++) {
                __half hh = __float2half(x[j] * di);
                pk.h[j] = *(ushort*)&hh;
            }
            *((uint4*)(znext + o)) = pk.u;
        } else {
            float sdeg = (cnt > 0) ? sqrtf((float)cnt) : 0.0f;
            uint4 v2 = *((const uint4*)(zprev + o));  // z2 (own row)
            uint4 v3 = *((const uint4*)(z + o));      // z3 (own row)
            const __half2* h2 = (const __half2*)&v2;
            const __half2* h3 = (const __half2*)&v3;
            float4 e0 = ((const float4*)(emb + o))[0];
            float4 e1 = ((const float4*)(emb + o))[1];
            float zs[8];
#pragma unroll
            for (int j = 0; j < 4; j++) {
                float2 a2 = __half22float2(h2[j]);
                float2 a3 = __half22float2(h3[j]);
                zs[2 * j] = a2.x + a3.x;
                zs[2 * j + 1] = a2.y + a3.y;
            }
            float4 o0 = make_float4(
                (e0.x + sdeg * zs[0] + x[0]) * 0.25f,
                (e0.y + sdeg * zs[1] + x[1]) * 0.25f,
                (e0.z + sdeg * zs[2] + x[2]) * 0.25f,
                (e0.w + sdeg * zs[3] + x[3]) * 0.25f);
            float4 o1 = make_float4(
                (e1.x + sdeg * zs[4] + x[4]) * 0.25f,
                (e1.y + sdeg * zs[5] + x[5]) * 0.25f,
                (e1.z + sdeg * zs[6] + x[6]) * 0.25f,
                (e1.w + sdeg * zs[7] + x[7]) * 0.25f);
            ((float4*)(out + o))[0] = o0;
            ((float4*)(out + o))[1] = o1;
        }
    }
}

extern "C" void kernel_launch(void* const* d_in, const int* in_sizes, int n_in,
                              void* d_out, int out_size, void* d_ws, size_t ws_size,
                              hipStream_t stream) {
    const float* emb = (const float*)d_in[0];
    const int* ei = (const int*)d_in[1];  // [2, E]: row = ei[0:E], col = ei[E:2E]
    float* out = (float*)d_out;

    char* ws = (char*)d_ws;
    size_t off = 0;
    auto alloc = [&](size_t bytes) -> void* {
        void* p = ws + off;
        off += (bytes + 511) & ~(size_t)511;
        return p;
    };
    // persistent region
    int4* rec = (int4*)alloc((size_t)N_NODES * 16);
    float* dinv = (float*)alloc((size_t)N_NODES * 4);
    int* gcursor = (int*)alloc(NB * 4);
    int* bucketStart = (int*)alloc(NB * 4);
    int* csrc = (int*)alloc(((size_t)N_EDGES + 64) * 4);  // +64 overread slack
    // transient union: staging (14.4MB) dead after k_build; zA overlays it.
    // z buffers have N_NODES+1 rows; row N_NODES is the zero row.
    size_t zbytes = (size_t)(N_NODES + 1) * DIM * 2;  // 12.81 MB
    size_t stbytes = (size_t)NB * CAP * 4;            // 14.42 MB
    char* transient = (char*)alloc(stbytes > zbytes ? stbytes : zbytes);
    int* staging = (int*)transient;
    __half* zA = (__half*)transient;
    __half* zB = (__half*)alloc(zbytes);

    hipMemsetAsync(gcursor, 0, NB * 4, stream);

    k_bucket<<<NBLK1, 256, 0, stream>>>(ei, gcursor, staging);
    k_bstart<<<1, 256, 0, stream>>>(gcursor, bucketStart);
    k_build<<<NB, 256, 0, stream>>>(gcursor, bucketStart, staging, rec, dinv, csrc);
    // staging dead from here; zA overlays it. Tail threads zero zero-rows.
    k_z0<<<(N_NODES * DIM / 4) / 256 + 1, 256, 0, stream>>>(emb, dinv, zA, zB);

    int spmvBlocks = (N_NODES + 3) / 4;  // 4 waves/block, 1 wave/node
    // pass1: zA -> zB (z2); pass2: zB -> zA (z3); pass3: gathers zA, reads
    // zB(z2)+zA(z3) own rows, writes out.
    k_spmv<<<spmvBlocks, 256, 0, stream>>>(rec, csrc, zA, zB, nullptr, emb, out, 0);
    k_spmv<<<spmvBlocks, 256, 0, stream>>>(rec, csrc, zB, zA, nullptr, emb, out, 0);
    k_spmv<<<spmvBlocks, 256, 0, stream>>>(rec, csrc, zA, nullptr, zB, emb, out, 2);
}

// Round 6
// 307.891 us; speedup vs baseline: 1.0946x; 1.0946x over previous
//
#include <hip/hip_runtime.h>
#include <hip/hip_bf16.h>
#include <hip/hip_fp16.h>
#include <stdint.h>

// LightGCN on MI355X, round 9.
// R8 post-mortem: NB=782 killed k_bucket (37KB LDS -> 28% occupancy, 1.4M
// bank-conflict cycles, 79us top dispatch). Bucket count must be decoupled:
// k_bucket wants FEW buckets, k_build wants MANY blocks.
// R9: NB=196 (512-node buckets, R6/R7-proven k_bucket config, uchar sbkt)
// + k_build with 4 sub-blocks per bucket (grid 784 ~ 3/CU): each sub-block
// streams the bucket segment, counts all 512 nodes in LDS (redundant,
// no inter-block comms), scatters only its 128-node quarter (contiguous
// csrc sub-range -> single-owner write combining preserved). k_bstart
// folded into k_build (each block scans gcursor[196] in LDS).
// spmv/k_z0 unchanged from R8 (z-only writes, rec int4 broadcast).

#define N_NODES 100000
#define N_EDGES 3200000
#define DIM 64

#define BSH 9                // 512 nodes per bucket
#define BNODES 512
#define NB 196               // ceil(100000/512)
#define CAP 20480            // staging slots per bucket (mean 16327)

#define CHUNK 8192           // edges per k_bucket block
#define NBLK1 ((N_EDGES + CHUNK - 1) / CHUNK)  // 391

// ---- level 1: bucket edges by dst range (dst>>9) ----
__global__ __launch_bounds__(256) void k_bucket(const int* __restrict__ ei,
                                                int* __restrict__ gcursor,
                                                int* __restrict__ staging) {
    __shared__ int stage[CHUNK];            // packed (row<<9)|dstLocal
    __shared__ unsigned char sbkt[CHUNK];   // bucket id per staged entry
    __shared__ int bcnt[NB];
    __shared__ int boff[NB];
    __shared__ int bstart[NB];
    __shared__ int gbase[NB];
    __shared__ int wt[4];

    int t = threadIdx.x;
    int e0 = blockIdx.x * CHUNK;
    int nblk = min(CHUNK, N_EDGES - e0);
    int nvec = nblk >> 2;

    const int4* col4 = (const int4*)(ei + N_EDGES + e0);
    const int4* row4 = (const int4*)(ei + e0);

    for (int i = t; i < NB; i += 256) { bcnt[i] = 0; boff[i] = 0; }
    __syncthreads();

    // phase A: count per bucket
    for (int i = t; i < nvec; i += 256) {
        int4 c = col4[i];
        atomicAdd(&bcnt[c.x >> BSH], 1);
        atomicAdd(&bcnt[c.y >> BSH], 1);
        atomicAdd(&bcnt[c.z >> BSH], 1);
        atomicAdd(&bcnt[c.w >> BSH], 1);
    }
    __syncthreads();

    // phase B: exclusive scan of bcnt -> bstart; reserve global runs
    {
        int v = (t < NB) ? bcnt[t] : 0;
        int lane = t & 63, w = t >> 6;
        int s = v;
#pragma unroll
        for (int off = 1; off < 64; off <<= 1) {
            int u = __shfl_up(s, off);
            if (lane >= off) s += u;
        }
        if (lane == 63) wt[w] = s;
        __syncthreads();
        int wo = 0;
        for (int ww = 0; ww < w; ww++) wo += wt[ww];
        if (t < NB) {
            bstart[t] = s - v + wo;
            gbase[t] = (v > 0) ? atomicAdd(&gcursor[t], v) : 0;
        }
    }
    __syncthreads();

    // phase C: place edges into LDS, bucket-sorted; remember bucket id
    for (int i = t; i < nvec; i += 256) {
        int4 c = col4[i];
        int4 r = row4[i];
        int b0 = c.x >> BSH, b1 = c.y >> BSH, b2 = c.z >> BSH, b3 = c.w >> BSH;
        int p0 = bstart[b0] + atomicAdd(&boff[b0], 1);
        int p1 = bstart[b1] + atomicAdd(&boff[b1], 1);
        int p2 = bstart[b2] + atomicAdd(&boff[b2], 1);
        int p3 = bstart[b3] + atomicAdd(&boff[b3], 1);
        stage[p0] = (r.x << BSH) | (c.x & (BNODES - 1)); sbkt[p0] = (unsigned char)b0;
        stage[p1] = (r.y << BSH) | (c.y & (BNODES - 1)); sbkt[p1] = (unsigned char)b1;
        stage[p2] = (r.z << BSH) | (c.z & (BNODES - 1)); sbkt[p2] = (unsigned char)b2;
        stage[p3] = (r.w << BSH) | (c.w & (BNODES - 1)); sbkt[p3] = (unsigned char)b3;
    }
    __syncthreads();

    // phase D: flush runs contiguously (coalesced across the wave)
    for (int i = t; i < nblk; i += 256) {
        int e = stage[i];
        int b = sbkt[i];
        staging[(size_t)b * CAP + gbase[b] + (i - bstart[b])] = e;
    }
}

// ---- level 2: per-bucket CSR build; 4 sub-blocks per bucket ----
// Each sub-block: scans gcursor (bucketStart), counts ALL 512 nodes in LDS
// (redundant across the 4), scatters only its 128-node quarter into the
// quarter's contiguous csrc sub-range.
__global__ __launch_bounds__(256) void k_build(const int* __restrict__ gcursor,
                                               const int* __restrict__ staging,
                                               int4* __restrict__ rec,
                                               float* __restrict__ dinv,
                                               int* __restrict__ csrc) {
    __shared__ int ldeg[BNODES];
    __shared__ int lcur[BNODES];
    __shared__ int gsc[NB];
    __shared__ int wtt[4];

    int b = blockIdx.x >> 2;
    int q = blockIdx.x & 3;
    int t = threadIdx.x;
    int n0 = b << BSH;
    int nloc = min(BNODES, N_NODES - n0);
    int cnt = gcursor[b];
    const int* st = staging + (size_t)b * CAP;

    // bucketStart[b] via in-block exclusive scan of gcursor[0..NB)
    {
        int v = (t < NB) ? gcursor[t] : 0;
        int lane = t & 63, w = t >> 6;
        int ss = v;
#pragma unroll
        for (int off = 1; off < 64; off <<= 1) {
            int u = __shfl_up(ss, off);
            if (lane >= off) ss += u;
        }
        if (lane == 63) wtt[w] = ss;
        ldeg[t] = 0; ldeg[t + 256] = 0;
        __syncthreads();
        int wo = 0;
        for (int ww = 0; ww < w; ww++) wo += wtt[ww];
        if (t < NB) gsc[t] = ss - v + wo;
    }
    __syncthreads();
    int bstartB = gsc[b];

    // count ALL nodes of the bucket (each sub-block redundantly)
    for (int i = t; i < cnt; i += 256) {
        atomicAdd(&ldeg[st[i] & (BNODES - 1)], 1);
    }
    __syncthreads();

    // block scan over 512 counters (2 per thread)
    int a0 = ldeg[2 * t], a1 = ldeg[2 * t + 1];
    int s = a0 + a1;
    int lane = t & 63, w = t >> 6;
    int ss = s;
#pragma unroll
    for (int off = 1; off < 64; off <<= 1) {
        int u = __shfl_up(ss, off);
        if (lane >= off) ss += u;
    }
    if (lane == 63) wtt[w] = ss;
    __syncthreads();
    int wo = 0;
    for (int ww = 0; ww < w; ww++) wo += wtt[ww];
    int excl = ss - s + wo;

    int gb = bstartB + excl;
    int n = n0 + 2 * t;
    lcur[2 * t] = gb;
    lcur[2 * t + 1] = gb + a0;
    // nodes 2t and 2t+1 are always in the same 128-quarter (2t even)
    if (((2 * t) >> 7) == q) {
        if (2 * t < nloc) {
            float di = (a0 > 0) ? rsqrtf((float)a0) : 0.0f;
            rec[n] = make_int4(gb, a0, __float_as_int(di), 0);
            dinv[n] = di;
        }
        if (2 * t + 1 < nloc) {
            float di = (a1 > 0) ? rsqrtf((float)a1) : 0.0f;
            rec[n + 1] = make_int4(gb + a0, a1, __float_as_int(di), 0);
            dinv[n + 1] = di;
        }
    }
    __syncthreads();

    // scatter only this quarter's nodes (contiguous csrc sub-range,
    // single owner -> L2 write combining)
    for (int i = t; i < cnt; i += 256) {
        int e = st[i];
        int dl = e & (BNODES - 1);
        if ((dl >> 7) == q) {
            int p = atomicAdd(&lcur[dl], 1);
            csrc[p] = e >> BSH;
        }
    }
}

// z0 = fp16(emb * dinv[node]); tail threads zero the zero rows of zA/zB
__global__ void k_z0(const float* __restrict__ emb, const float* __restrict__ dinv,
                     __half* __restrict__ zA, __half* __restrict__ zB) {
    const int total = (N_NODES * DIM) / 4;  // 1.6M groups of 4
    int i = blockIdx.x * blockDim.x + threadIdx.x;
    if (i >= total) {
        int r = i - total;
        if (r < 16) ((uint2*)(zA + (size_t)N_NODES * DIM))[r] = make_uint2(0, 0);
        else if (r < 32) ((uint2*)(zB + (size_t)N_NODES * DIM))[r - 16] = make_uint2(0, 0);
        return;
    }
    float di = dinv[(i * 4) >> 6];
    const float4 v = ((const float4*)emb)[i];
    union { ushort h[4]; uint2 u; } pk;
    __half h0 = __float2half(v.x * di);
    __half h1 = __float2half(v.y * di);
    __half h2 = __float2half(v.z * di);
    __half h3 = __float2half(v.w * di);
    pk.h[0] = *(ushort*)&h0; pk.h[1] = *(ushort*)&h1;
    pk.h[2] = *(ushort*)&h2; pk.h[3] = *(ushort*)&h3;
    ((uint2*)zA)[i] = pk.u;
}

// ---- SpMV: one wave per dst node; exact ceil(deg/8) gather groups of 8;
// fp16 rows, packed half2 accumulate; invalid slots -> zero row.
// mode 0: write z_out = x*dinv (fp16) only.
// mode 2: final: out = 0.25*(emb + sqrt(deg)*(z2+z3) + x3); no z write.
__global__ __launch_bounds__(256) void k_spmv(
    const int4* __restrict__ rec, const int* __restrict__ csrc,
    const __half* __restrict__ z, __half* __restrict__ znext,
    const __half* __restrict__ zprev, const float* __restrict__ emb,
    float* __restrict__ out, int mode) {
    int wave = (blockIdx.x * blockDim.x + threadIdx.x) >> 6;
    int lane = threadIdx.x & 63;
    if (wave >= N_NODES) return;
    int g = lane >> 3;   // edge slot within group 0..7
    int l = lane & 7;    // feature chunk: features [l*8, l*8+8)

    int4 nr = rec[wave];          // broadcast load
    int start = nr.x;
    int cnt = nr.y;
    float di = __int_as_float(nr.z);
    int ng = (cnt + 7) >> 3;      // gather groups (wave-uniform)

    __half2 hz = __float2half2_rn(0.0f);
    __half2 hacc0 = hz, hacc1 = hz, hacc2 = hz, hacc3 = hz;

#define GLOAD(KK, SVAR)                              \
    int e##SVAR = (KK) * 8 + g;                      \
    int SVAR = csrc[start + e##SVAR];                \
    SVAR = (e##SVAR < cnt) ? SVAR : N_NODES;

#define GACC(SVAR)                                                        \
    do {                                                                  \
        uint4 v = *((const uint4*)(z + ((size_t)SVAR << 6)) + l);         \
        const __half2* hv = (const __half2*)&v;                           \
        hacc0 = __hadd2(hacc0, hv[0]);                                    \
        hacc1 = __hadd2(hacc1, hv[1]);                                    \
        hacc2 = __hadd2(hacc2, hv[2]);                                    \
        hacc3 = __hadd2(hacc3, hv[3]);                                    \
    } while (0)

    int k = 0;
    for (; k + 4 <= ng; k += 4) {
        GLOAD(k + 0, s0); GLOAD(k + 1, s1); GLOAD(k + 2, s2); GLOAD(k + 3, s3);
        GACC(s0); GACC(s1); GACC(s2); GACC(s3);
    }
    int rem = ng - k;           // wave-uniform 0..3
    if (rem > 0) {
        GLOAD(k + 0, t0);
        if (rem > 1) { GLOAD(k + 1, t1);
            if (rem > 2) { GLOAD(k + 2, t2); GACC(t0); GACC(t1); GACC(t2); }
            else { GACC(t0); GACC(t1); }
        } else { GACC(t0); }
    }
#undef GLOAD
#undef GACC

    // packed reduce across the 8 edge-slot groups (lane bits 3,4,5)
#pragma unroll
    for (int off = 8; off <= 32; off <<= 1) {
        int b0 = __shfl_xor(*(int*)&hacc0, off);
        int b1 = __shfl_xor(*(int*)&hacc1, off);
        int b2 = __shfl_xor(*(int*)&hacc2, off);
        int b3 = __shfl_xor(*(int*)&hacc3, off);
        hacc0 = __hadd2(hacc0, *(__half2*)&b0);
        hacc1 = __hadd2(hacc1, *(__half2*)&b1);
        hacc2 = __hadd2(hacc2, *(__half2*)&b2);
        hacc3 = __hadd2(hacc3, *(__half2*)&b3);
    }

    if (lane < 8) {  // lane == l, holds features [l*8, l*8+8)
        size_t o = (size_t)wave * DIM + lane * 8;
        float x[8];   // x_{k+1} for this node = di * sum
        x[0] = __low2float(hacc0) * di; x[1] = __high2float(hacc0) * di;
        x[2] = __low2float(hacc1) * di; x[3] = __high2float(hacc1) * di;
        x[4] = __low2float(hacc2) * di; x[5] = __high2float(hacc2) * di;
        x[6] = __low2float(hacc3) * di; x[7] = __high2float(hacc3) * di;

        if (mode == 0) {
            union { ushort h[8]; uint4 u; } pk;
#pragma unroll
            for (int j = 0; j < 8; j++) {
                __half hh = __float2half(x[j] * di);
                pk.h[j] = *(ushort*)&hh;
            }
            *((uint4*)(znext + o)) = pk.u;
        } else {
            float sdeg = (cnt > 0) ? sqrtf((float)cnt) : 0.0f;
            uint4 v2 = *((const uint4*)(zprev + o));  // z2 (own row)
            uint4 v3 = *((const uint4*)(z + o));      // z3 (own row)
            const __half2* h2 = (const __half2*)&v2;
            const __half2* h3 = (const __half2*)&v3;
            float4 e0 = ((const float4*)(emb + o))[0];
            float4 e1 = ((const float4*)(emb + o))[1];
            float zs[8];
#pragma unroll
            for (int j = 0; j < 4; j++) {
                float2 a2 = __half22float2(h2[j]);
                float2 a3 = __half22float2(h3[j]);
                zs[2 * j] = a2.x + a3.x;
                zs[2 * j + 1] = a2.y + a3.y;
            }
            float4 o0 = make_float4(
                (e0.x + sdeg * zs[0] + x[0]) * 0.25f,
                (e0.y + sdeg * zs[1] + x[1]) * 0.25f,
                (e0.z + sdeg * zs[2] + x[2]) * 0.25f,
                (e0.w + sdeg * zs[3] + x[3]) * 0.25f);
            float4 o1 = make_float4(
                (e1.x + sdeg * zs[4] + x[4]) * 0.25f,
                (e1.y + sdeg * zs[5] + x[5]) * 0.25f,
                (e1.z + sdeg * zs[6] + x[6]) * 0.25f,
                (e1.w + sdeg * zs[7] + x[7]) * 0.25f);
            ((float4*)(out + o))[0] = o0;
            ((float4*)(out + o))[1] = o1;
        }
    }
}

extern "C" void kernel_launch(void* const* d_in, const int* in_sizes, int n_in,
                              void* d_out, int out_size, void* d_ws, size_t ws_size,
                              hipStream_t stream) {
    const float* emb = (const float*)d_in[0];
    const int* ei = (const int*)d_in[1];  // [2, E]: row = ei[0:E], col = ei[E:2E]
    float* out = (float*)d_out;

    char* ws = (char*)d_ws;
    size_t off = 0;
    auto alloc = [&](size_t bytes) -> void* {
        void* p = ws + off;
        off += (bytes + 511) & ~(size_t)511;
        return p;
    };
    // persistent region
    int4* rec = (int4*)alloc((size_t)N_NODES * 16);
    float* dinv = (float*)alloc((size_t)N_NODES * 4);
    int* gcursor = (int*)alloc(NB * 4);
    int* csrc = (int*)alloc(((size_t)N_EDGES + 64) * 4);  // +64 overread slack
    // transient union: staging (16MB) dead after k_build; zA overlays it.
    // z buffers have N_NODES+1 rows; row N_NODES is the zero row.
    size_t zbytes = (size_t)(N_NODES + 1) * DIM * 2;  // 12.81 MB
    size_t stbytes = (size_t)NB * CAP * 4;            // 16.05 MB
    char* transient = (char*)alloc(stbytes > zbytes ? stbytes : zbytes);
    int* staging = (int*)transient;
    __half* zA = (__half*)transient;
    __half* zB = (__half*)alloc(zbytes);

    hipMemsetAsync(gcursor, 0, NB * 4, stream);

    k_bucket<<<NBLK1, 256, 0, stream>>>(ei, gcursor, staging);
    k_build<<<NB * 4, 256, 0, stream>>>(gcursor, staging, rec, dinv, csrc);
    // staging dead from here; zA overlays it. Tail threads zero zero-rows.
    k_z0<<<(N_NODES * DIM / 4) / 256 + 1, 256, 0, stream>>>(emb, dinv, zA, zB);

    int spmvBlocks = (N_NODES + 3) / 4;  // 4 waves/block, 1 wave/node
    // pass1: zA -> zB (z2); pass2: zB -> zA (z3); pass3: gathers zA, reads
    // zB(z2)+zA(z3) own rows, writes out.
    k_spmv<<<spmvBlocks, 256, 0, stream>>>(rec, csrc, zA, zB, nullptr, emb, out, 0);
    k_spmv<<<spmvBlocks, 256, 0, stream>>>(rec, csrc, zB, zA, nullptr, emb, out, 0);
    k_spmv<<<spmvBlocks, 256, 0, stream>>>(rec, csrc, zA, nullptr, zB, emb, out, 2);
}